// Round 7
// baseline (636.167 us; speedup 1.0000x reference)
//
#include <hip/hip_runtime.h>

#define B_ 4
#define N_ 8192
#define DIN 64
#define HDIM 64
#define DOUT 128
#define KNN 16
#define QPB 64               // queries per block (= lanes per wave)
#define PART 8               // partner waves per query block
#define NTHR (QPB * PART)    // 512 threads / block
#define CHUNK2 512           // candidates per wave (half-block split)
#define CAP 16               // deferred-insert buffer slots per thread (idx only)
#define CAPP 17              // padded per-lane stride
#define BLOCKS_PER_B (N_ / QPB)  // 128

// ---------------- K_prep: pack (x,y,z,sq) + compose affine params ----------------
__global__ __launch_bounds__(256) void k_prep(
    const float* __restrict__ xyz,
    const float* __restrict__ w1, const float* __restrict__ b1,
    const float* __restrict__ w2, const float* __restrict__ b2,
    const float* __restrict__ w3, const float* __restrict__ b3,
    float4* __restrict__ pk, float4* __restrict__ prm) {
  const int blk = blockIdx.x, t = threadIdx.x;
  const int b = blk >> 5;
  const int m = ((blk & 31) << 8) + t;
  const float* xb = xyz + (size_t)b * 3 * N_;
  float x = xb[m], y = xb[N_ + m], z = xb[2 * N_ + m];
  float sq = __fadd_rn(__fadd_rn(__fmul_rn(x, x), __fmul_rn(y, y)), __fmul_rn(z, z));
  pk[((size_t)b << 13) + m] = make_float4(x, y, z, sq);

  if (blk == 0) {
    __shared__ float M2[HDIM][10];
    __shared__ float bb[HDIM];
    const int o = t;
    if (o < HDIM) {
      float r[10];
#pragma unroll
      for (int c = 0; c < 10; c++) r[c] = 0.f;
      float s = b2[o];
      for (int l = 0; l < HDIM; l++) {
        float w = w2[o * HDIM + l];
#pragma unroll
        for (int c = 0; c < 10; c++) r[c] = fmaf(w, w1[l * 10 + c], r[c]);
        s = fmaf(w, b1[l], s);
      }
#pragma unroll
      for (int c = 0; c < 10; c++) M2[o][c] = r[c];
      bb[o] = s;
    }
    __syncthreads();
    if (o < HDIM) {
      float r3[10];
#pragma unroll
      for (int c = 0; c < 10; c++) r3[c] = 0.f;
      float bc = b3[o];
      for (int l = 0; l < HDIM; l++) {
        float w = w3[o * HDIM + l];
#pragma unroll
        for (int c = 0; c < 10; c++) r3[c] = fmaf(w, M2[l][c], r3[c]);
        bc = fmaf(w, bb[l], bc);
      }
      prm[o]      = make_float4(r3[0] - r3[6], r3[1] - r3[7], r3[2] - r3[8], bc);
      prm[64 + o] = make_float4(r3[3] + r3[6], r3[4] + r3[7], r3[5] + r3[8], r3[9]);
    }
  }
}

// max of 16 via v_max3-friendly triple nesting
#define MAX16(VARR, VMAX)                                                     \
  {                                                                           \
    float _m0 = fmaxf(fmaxf(VARR[0], VARR[1]), VARR[2]);                      \
    float _m1 = fmaxf(fmaxf(VARR[3], VARR[4]), VARR[5]);                      \
    float _m2 = fmaxf(fmaxf(VARR[6], VARR[7]), VARR[8]);                      \
    float _m3 = fmaxf(fmaxf(VARR[9], VARR[10]), VARR[11]);                    \
    float _m4 = fmaxf(fmaxf(VARR[12], VARR[13]), VARR[14]);                   \
    float _a = fmaxf(fmaxf(_m0, _m1), _m2);                                   \
    float _b = fmaxf(fmaxf(_m3, _m4), VARR[15]);                              \
    VMAX = fmaxf(_a, _b);                                                     \
  }

// replace-max insert into unsorted top-16 kept in registers (fully unrolled)
#define INSERT16(VARR, IARR, VMAX, DVAL, MIDX)                    \
  {                                                               \
    bool done = false;                                            \
    _Pragma("unroll") for (int _i = 0; _i < KNN; _i++) {          \
      bool hit = (!done) && (VARR[_i] == VMAX);                   \
      if (hit) { VARR[_i] = (DVAL); IARR[_i] = (MIDX); }          \
      done = done | hit;                                          \
    }                                                             \
    MAX16(VARR, VMAX);                                            \
  }

// drain idx-only buffer: re-gather candidates from pk (L2, 8-wide batches for
// MLP), recompute EXACT reference-rounded d, insert in push order. Publish tau
// via atomicMin's returned old value (no LDS read-back).
#define FLUSH()                                                               \
  {                                                                           \
    _Pragma("unroll") for (int c0_ = 0; c0_ < CAP; c0_ += 8) {                \
      int mi_[8]; float4 fc_[8];                                              \
      _Pragma("unroll") for (int e_ = 0; e_ < 8; e_++)                        \
        mi_[e_] = scanI[lbase + c0_ + e_] & (N_ - 1);                         \
      _Pragma("unroll") for (int e_ = 0; e_ < 8; e_++)                        \
        fc_[e_] = pk[bb + mi_[e_]];                                           \
      _Pragma("unroll") for (int e_ = 0; e_ < 8; e_++) {                      \
        if (c0_ + e_ < cnt) {                                                 \
          float dot_ = fmaf(fc_[e_].z, qz,                                    \
                       fmaf(fc_[e_].y, qy, __fmul_rn(fc_[e_].x, qx)));        \
          float d_ = fmaf(-2.0f, dot_, __fadd_rn(qs, fc_[e_].w));             \
          if (d_ < vmax) { INSERT16(v, id, vmax, d_, mi_[e_]); }              \
        }                                                                     \
      }                                                                       \
    }                                                                         \
    cnt = 0;                                                                  \
    unsigned old_ = atomicMin(&tau[q], __float_as_uint(vmax));                \
    gate = fminf(vmax, __uint_as_float(old_));                                \
  }

// process one 8-candidate batch (wave-uniform regs): exact-d filter (5 VALU +
// cmp; fmaf(-2,dot,qs+cw) == (qs+cw)-2*dot bit-exactly), idx-only push.
#define PROC8(CARR, U0)                                                       \
  {                                                                           \
    if (__any(cnt > CAP - 8)) { FLUSH(); }                                    \
    gate = fminf(gate, __uint_as_float(tnext));                               \
    tnext = tau[q];                                                           \
    _Pragma("unroll") for (int e = 0; e < 8; e++) {                           \
      float dot_ = fmaf(CARR[e].z, qz,                                        \
                   fmaf(CARR[e].y, qy, __fmul_rn(CARR[e].x, qx)));            \
      float d_ = fmaf(-2.0f, dot_, __fadd_rn(qs, CARR[e].w));                 \
      if (d_ < gate) {                                                        \
        scanI[lbase + cnt] = (unsigned short)(base + (U0) + e);               \
        cnt++;                                                                \
      }                                                                       \
    }                                                                         \
  }

// ---------------- K_knn: scan + in-block merge, half-split for occupancy ------
// Grid = B*256: each 64-query group is covered by TWO blocks (h=0: m<4096,
// h=1: m>=4096), 8 waves x 512 candidates each -> 8192 waves = 100% structural
// occupancy (vs 50% before). LDS = 24.3KB (scan idx-buffer overlapped with the
// merge exchange) -> 4 blocks/CU. Scan loop is the best-measured R4 structure
// verbatim. Each half writes its final 16 (id,d) per query into out rows
// h*32+[0..31] (bit-cast ids) -- k_fe merges the halves and overwrites out.
__global__ __launch_bounds__(NTHR, 8) void k_knn(
    const float4* __restrict__ pk, float* __restrict__ out) {
  const int blk = blockIdx.x;
  const int b   = blk >> 8;
  const int rem = blk & 255;
  const int n0  = (rem >> 1) * QPB;
  const int h   = rem & 1;
  const int t = threadIdx.x;
  const int q = t & 63;
  const int j = __builtin_amdgcn_readfirstlane(t >> 6);
  const int lbase = t * CAPP;
  const size_t bb = (size_t)b << 13;

  __shared__ unsigned tau[QPB];
  // 24KB, time-multiplexed: scan idx-buffer [512][17] ushort (17.4KB), then
  // merge exchange Xd float[64][64] (16KB) + Xi ushort[64][64] (8KB)
  __shared__ alignas(16) unsigned char poolRaw[24576];
  unsigned short* scanI = (unsigned short*)poolRaw;
  float* Xd = (float*)poolRaw;
  unsigned short* Xi = (unsigned short*)(poolRaw + 16384);

  if (t < QPB) tau[t] = 0x7f800000u;  // +inf

  const float4 qv = pk[bb + n0 + q];
  const float qx = qv.x, qy = qv.y, qz = qv.z, qs = qv.w;

  float v[KNN]; int id[KNN];
  float vmax, gate;
  int cnt = 0;
  __syncthreads();

  const int base = h * (PART * CHUNK2) + j * CHUNK2;
  const float4* pj = pk + bb + base;

  // warm start: first 16 candidates fill the list directly with exact d
  {
    float4 c[KNN];
#pragma unroll
    for (int e = 0; e < KNN; e++) c[e] = pj[e];
#pragma unroll
    for (int e = 0; e < KNN; e++) {
      float dot = fmaf(c[e].z, qz, fmaf(c[e].y, qy, __fmul_rn(c[e].x, qx)));
      v[e] = fmaf(-2.0f, dot, __fadd_rn(qs, c[e].w));
      id[e] = base + e;
    }
    MAX16(v, vmax);
    unsigned old = atomicMin(&tau[q], __float_as_uint(vmax));
    gate = fminf(vmax, __uint_as_float(old));
  }

  // ping-pong scalar-prefetched scan (R4-verbatim structure)
  {
    unsigned tnext = tau[q];
    float4 ca[8], cb[8];
#pragma unroll
    for (int e = 0; e < 8; e++) ca[e] = pj[KNN + e];
    for (int u0 = KNN; u0 < CHUNK2; u0 += 16) {
#pragma unroll
      for (int e = 0; e < 8; e++) cb[e] = pj[u0 + 8 + e];
      PROC8(ca, u0);
      int pf = (u0 + 16 < CHUNK2) ? u0 + 16 : 0;  // clamp: never read past chunk
#pragma unroll
      for (int e = 0; e < 8; e++) ca[e] = pj[pf + e];
      PROC8(cb, u0 + 8);
    }
  }
  FLUSH();
  __syncthreads();  // scan buffer dead; exchange X usable

  // tree merge in ascending-m order (tie semantics preserved: strict <, left
  // list = lower m kept as base, right folded in list order)
  float fv[KNN]; int fid[KNN]; float fm = vmax;
#pragma unroll
  for (int i = 0; i < KNN; i++) { fv[i] = v[i]; fid[i] = id[i]; }

  // stage A: odd waves publish; even wave j folds wave j+1
  if (j & 1) {
    const int s = j >> 1;
#pragma unroll
    for (int i = 0; i < KNN; i++) {
      Xd[(s * KNN + i) * QPB + q] = fv[i];
      Xi[(s * KNN + i) * QPB + q] = (unsigned short)fid[i];
    }
  }
  __syncthreads();
  if (!(j & 1)) {
    const int s = j >> 1;
    for (int ss = 0; ss < KNN; ss++) {
      float d = Xd[(s * KNN + ss) * QPB + q];
      if (d < fm) { int m_ = Xi[(s * KNN + ss) * QPB + q]; INSERT16(fv, fid, fm, d, m_); }
    }
  }
  __syncthreads();
  // stage B: waves 2,6 publish slots 0,1; waves 0,4 fold
  if (j == 2 || j == 6) {
    const int s = j >> 2;
#pragma unroll
    for (int i = 0; i < KNN; i++) {
      Xd[(s * KNN + i) * QPB + q] = fv[i];
      Xi[(s * KNN + i) * QPB + q] = (unsigned short)fid[i];
    }
  }
  __syncthreads();
  if (j == 0 || j == 4) {
    const int s = j >> 2;
    for (int ss = 0; ss < KNN; ss++) {
      float d = Xd[(s * KNN + ss) * QPB + q];
      if (d < fm) { int m_ = Xi[(s * KNN + ss) * QPB + q]; INSERT16(fv, fid, fm, d, m_); }
    }
  }
  __syncthreads();
  // stage C: wave 4 publishes; wave 0 folds -> half-final list
  if (j == 4) {
#pragma unroll
    for (int i = 0; i < KNN; i++) {
      Xd[i * QPB + q] = fv[i];
      Xi[i * QPB + q] = (unsigned short)fid[i];
    }
  }
  __syncthreads();
  if (j == 0) {
    for (int ss = 0; ss < KNN; ss++) {
      float d = Xd[ss * QPB + q];
      if (d < fm) { int m_ = Xi[ss * QPB + q]; INSERT16(fv, fid, fm, d, m_); }
    }
    // publish half-result into out rows h*32 + [0..15]=ids(bitcast), [16..31]=d
    float* ob = out + (size_t)b * DOUT * N_ + n0 + q;
#pragma unroll
    for (int i = 0; i < KNN; i++) {
      ob[(size_t)(h * 32 + i) * N_]       = __uint_as_float((unsigned)fid[i]);
      ob[(size_t)(h * 32 + KNN + i) * N_] = fv[i];
    }
  }
}

// ---------------- K_fe: merge halves + gather + fe + shortcut GEMM ------------
__global__ __launch_bounds__(NTHR, 2) void k_fe(
    const float4* __restrict__ pk, const float4* __restrict__ prm,
    const float* __restrict__ feature, const float* __restrict__ wsM,
    const float* __restrict__ bs, float* __restrict__ out) {
  const int blk = blockIdx.x;
  const int b  = blk / BLOCKS_PER_B;
  const int n0 = (blk % BLOCKS_PER_B) * QPB;
  const int t = threadIdx.x;
  const int q = t & 63;
  const int j = __builtin_amdgcn_readfirstlane(t >> 6);
  const size_t bb = (size_t)b << 13;
  const float INF = __uint_as_float(0x7f800000u);

  __shared__ float4 prmL[2 * HDIM];              // 2 KB
  __shared__ float gp[4 * KNN * QPB];            // 16 KB: neighbor x/y/z/dsq rows
  __shared__ float feL[DIN * QPB];               // 16 KB feature tile
  __shared__ alignas(16) float wsL[DOUT * DIN];  // 32 KB ws

  for (int i = t; i < 2 * HDIM; i += NTHR) prmL[i] = prm[i];
  for (int i = t; i < DOUT * DIN / 4; i += NTHR)
    ((float4*)wsL)[i] = ((const float4*)wsM)[i];
#pragma unroll
  for (int r = 0; r < 8; r++) {
    int c = j * 8 + r;
    feL[c * QPB + q] = feature[(size_t)(b * DIN + c) * N_ + n0 + q];
  }

  const float4 qv = pk[bb + n0 + q];
  const float qx = qv.x, qy = qv.y, qz = qv.z;

  float* ob = out + (size_t)b * DOUT * N_ + n0 + q;

  // merge the two half-lists (each thread redundantly; h0 base, fold h1;
  // strict < keeps lower-m half on ties -- identical to single-block fold)
  float fv[KNN]; int fid[KNN]; float fm;
#pragma unroll
  for (int i = 0; i < KNN; i++) {
    fid[i] = (int)(__float_as_uint(ob[(size_t)i * N_]) & (N_ - 1));
    fv[i]  = ob[(size_t)(KNN + i) * N_];
  }
  MAX16(fv, fm);
  for (int s = 0; s < KNN; s++) {
    float d = ob[(size_t)(48 + s) * N_];
    if (d < fm) {
      int m_ = (int)(__float_as_uint(ob[(size_t)(32 + s) * N_]) & (N_ - 1));
      INSERT16(fv, fid, fm, d, m_);
    }
  }

  // gather neighbors (2 per wave-slot) into gp rows
#pragma unroll
  for (int kk = 0; kk < 2; kk++) {
    int k = j * 2 + kk;
    int m = fid[k];
    float4 c = pk[bb + m];
    float dx = __fsub_rn(c.x, qx), dy = __fsub_rn(c.y, qy), dz = __fsub_rn(c.z, qz);
    float dsq = __fadd_rn(__fadd_rn(__fmul_rn(dx, dx), __fmul_rn(dy, dy)),
                          __fmul_rn(dz, dz));
    gp[k * QPB + q] = c.x;
    gp[(KNN + k) * QPB + q] = c.y;
    gp[(2 * KNN + k) * QPB + q] = c.z;
    gp[(3 * KNN + k) * QPB + q] = dsq;
  }
  __syncthreads();

  float fo[8];
  {
    float nx[KNN], ny[KNN], nz[KNN], nd[KNN];
#pragma unroll
    for (int k = 0; k < KNN; k++) {
      nx[k] = gp[k * QPB + q];
      ny[k] = gp[(KNN + k) * QPB + q];
      nz[k] = gp[(2 * KNN + k) * QPB + q];
      nd[k] = gp[(3 * KNN + k) * QPB + q];
    }
#pragma unroll
    for (int oi = 0; oi < 8; oi++) {
      int o = j * 8 + oi;
      float4 pA = prmL[o], pB = prmL[HDIM + o];
      float basev = fmaf(qz, pA.z, fmaf(qy, pA.y, fmaf(qx, pA.x, pA.w)));
      float mx = -INF;
#pragma unroll
      for (int k = 0; k < KNN; k++) {
        float tv = fmaf(nz[k], pB.z,
                   fmaf(ny[k], pB.y,
                   fmaf(nx[k], pB.x, __fmul_rn(nd[k], pB.w))));
        mx = fmaxf(mx, tv);
      }
      fo[oi] = basev + mx;
    }
  }

  // shortcut GEMM: wave j computes outputs o=j*8..j*8+7 and o+64 for its query q
  float acc[16];
#pragma unroll
  for (int oi = 0; oi < 16; oi++) acc[oi] = 0.f;
  for (int c4 = 0; c4 < DIN / 4; c4++) {
    float f0 = feL[(4 * c4 + 0) * QPB + q];
    float f1 = feL[(4 * c4 + 1) * QPB + q];
    float f2 = feL[(4 * c4 + 2) * QPB + q];
    float f3 = feL[(4 * c4 + 3) * QPB + q];
#pragma unroll
    for (int oi = 0; oi < 16; oi++) {
      int o = (oi < 8) ? (j * 8 + oi) : (64 + j * 8 + oi - 8);
      float4 w = ((const float4*)(wsL + o * DIN))[c4];  // wave-uniform broadcast
      acc[oi] = fmaf(w.x, f0, acc[oi]);
      acc[oi] = fmaf(w.y, f1, acc[oi]);
      acc[oi] = fmaf(w.z, f2, acc[oi]);
      acc[oi] = fmaf(w.w, f3, acc[oi]);
    }
  }
#pragma unroll
  for (int oi = 0; oi < 16; oi++) {
    int o = (oi < 8) ? (j * 8 + oi) : (64 + j * 8 + oi - 8);
    ob[(size_t)o * N_] = acc[oi] + bs[o] + fo[oi & 7];
  }
}

extern "C" void kernel_launch(void* const* d_in, const int* in_sizes, int n_in,
                              void* d_out, int out_size, void* d_ws, size_t ws_size,
                              hipStream_t stream) {
  const float* xyz     = (const float*)d_in[0];
  const float* feature = (const float*)d_in[1];
  const float* w1 = (const float*)d_in[2];
  const float* b1 = (const float*)d_in[3];
  const float* w2 = (const float*)d_in[4];
  const float* b2 = (const float*)d_in[5];
  const float* w3 = (const float*)d_in[6];
  const float* b3 = (const float*)d_in[7];
  const float* wsM = (const float*)d_in[8];
  const float* bs  = (const float*)d_in[9];
  float* out = (float*)d_out;

  // workspace: [0,8KB) prm, [8KB, 8KB+512KB) packed pk
  float4* prm = (float4*)d_ws;
  float4* pkB = (float4*)((char*)d_ws + 8192);

  hipLaunchKernelGGL(k_prep, dim3(128), dim3(256), 0, stream,
                     xyz, w1, b1, w2, b2, w3, b3, pkB, prm);
  hipLaunchKernelGGL(k_knn, dim3(B_ * 256), dim3(NTHR), 0, stream,
                     pkB, out);
  hipLaunchKernelGGL(k_fe, dim3(B_ * BLOCKS_PER_B), dim3(NTHR), 0, stream,
                     pkB, prm, feature, wsM, bs, out);
}